// Round 3
// baseline (3760.038 us; speedup 1.0000x reference)
//
#include <hip/hip_runtime.h>

#define LAYERS 6
#define NH 16
#define DIM 1024
#define VOCAB 32000
#define SEQ 2048
#define NBATCH 2
#define HEADD 64
#define NROW (NBATCH*SEQ)   // 4096
#define FF 4096
#define LN_EPS 1e-5f

typedef unsigned short bfu;  // bf16 bits
typedef __attribute__((ext_vector_type(8))) short s16x8;
typedef __attribute__((ext_vector_type(4))) float f32x4;

__device__ __forceinline__ float bf2f(bfu u) { return __uint_as_float(((unsigned)u) << 16); }
__device__ __forceinline__ bfu f2bf(float x) {
  unsigned u = __float_as_uint(x);
  return (bfu)((u + 0x7fffu + ((u >> 16) & 1u)) >> 16);  // RNE
}

__device__ __forceinline__ void gload16(const void* g, void* l) {
  __builtin_amdgcn_global_load_lds((const __attribute__((address_space(1))) void*)g,
                                   (__attribute__((address_space(3))) void*)l, 16, 0, 0);
}

__device__ __forceinline__ f32x4 mfma32(s16x8 a, s16x8 b, f32x4 c) {
  return __builtin_amdgcn_mfma_f32_16x16x32_bf16(a, b, c, 0, 0, 0);
}

// read element i of a float tensor that is either fp32 (f32=true) or bf16
__device__ __forceinline__ float rdf(const void* p, size_t i, bool f32) {
  return f32 ? ((const float*)p)[i] : bf2f(((const bfu*)p)[i]);
}

// ---------------- dtype detector: flag=1 if inputs are fp32, 0 if bf16 ----------------
__global__ __launch_bounds__(256) void detect_kernel(const unsigned* __restrict__ tok,
                                                     int* __restrict__ flag) {
  int cnt = 0;
  for (int i = threadIdx.x; i < 8192; i += 256) {
    unsigned e = (tok[i] >> 7) & 0xFFu;   // exponent field of LOW bf16 (if bf16 pairs)
    cnt += (e >= 96u && e <= 132u) ? 1 : 0;
  }
  for (int o = 32; o; o >>= 1) cnt += __shfl_xor(cnt, o);
  __shared__ int r[4];
  if ((threadIdx.x & 63) == 0) r[threadIdx.x >> 6] = cnt;
  __syncthreads();
  if (threadIdx.x == 0) *flag = ((r[0] + r[1] + r[2] + r[3]) < 4915) ? 1 : 0;
}

// ---------------- transpose+convert: out[C,R] (bf16) = in[eoff..][R,C]^T ----------------
__global__ __launch_bounds__(256) void tkernel(const void* __restrict__ in, size_t eoff,
                                               bfu* __restrict__ out, int R, int C,
                                               const int* __restrict__ flag) {
  __shared__ bfu tile[32][33];
  const bool f32 = *flag != 0;
  int tx = threadIdx.x, ty = threadIdx.y;
  int bx = blockIdx.x * 32, by = blockIdx.y * 32;
#pragma unroll
  for (int i = 0; i < 4; ++i)
    tile[ty + i * 8][tx] = f2bf(rdf(in, eoff + (size_t)(by + ty + i * 8) * C + bx + tx, f32));
  __syncthreads();
#pragma unroll
  for (int i = 0; i < 4; ++i)
    out[(size_t)(bx + ty + i * 8) * R + by + tx] = tile[tx][ty + i * 8];
}

// ---------------- embedding ----------------
__global__ __launch_bounds__(256) void embed_kernel(const int* __restrict__ idx,
                                                    const void* __restrict__ tok,
                                                    const void* __restrict__ pos,
                                                    const int* __restrict__ flag,
                                                    float* __restrict__ xf) {
  const bool f32 = *flag != 0;
  int row = blockIdx.x;
  int t = row % SEQ;
  int tokid = idx[row];
  int d0 = threadIdx.x * 4;
#pragma unroll
  for (int j = 0; j < 4; ++j) {
    int d = d0 + j;
    xf[(size_t)row * DIM + d] =
        rdf(tok, (size_t)tokid * DIM + d, f32) + rdf(pos, (size_t)t * DIM + d, f32);
  }
}

// ---------------- LayerNorm: x fp32 -> h bf16 (g/b at element offset eoff) ----------------
__global__ __launch_bounds__(256) void ln_kernel(const float* __restrict__ xf,
                                                 const void* __restrict__ gw,
                                                 const void* __restrict__ bw,
                                                 size_t eoff,
                                                 const int* __restrict__ flag,
                                                 bfu* __restrict__ h) {
  const bool f32 = *flag != 0;
  int row = blockIdx.x, tid = threadIdx.x;
  const float* xr = xf + (size_t)row * DIM;
  float4 xv4 = ((const float4*)xr)[tid];
  float xv[4] = {xv4.x, xv4.y, xv4.z, xv4.w};
  float s = xv[0] + xv[1] + xv[2] + xv[3];
  float ss = xv[0]*xv[0] + xv[1]*xv[1] + xv[2]*xv[2] + xv[3]*xv[3];
  for (int o = 32; o; o >>= 1) { s += __shfl_xor(s, o); ss += __shfl_xor(ss, o); }
  __shared__ float red[8];
  int wave = tid >> 6;
  if ((tid & 63) == 0) { red[wave * 2] = s; red[wave * 2 + 1] = ss; }
  __syncthreads();
  s  = red[0] + red[2] + red[4] + red[6];
  ss = red[1] + red[3] + red[5] + red[7];
  float mean = s * (1.0f / DIM);
  float var = ss * (1.0f / DIM) - mean * mean;
  float inv = rsqrtf(var + LN_EPS);
  int i0 = tid * 4;
  ushort4 hv;
  hv.x = f2bf((xv[0] - mean) * inv * rdf(gw, eoff + i0 + 0, f32) + rdf(bw, eoff + i0 + 0, f32));
  hv.y = f2bf((xv[1] - mean) * inv * rdf(gw, eoff + i0 + 1, f32) + rdf(bw, eoff + i0 + 1, f32));
  hv.z = f2bf((xv[2] - mean) * inv * rdf(gw, eoff + i0 + 2, f32) + rdf(bw, eoff + i0 + 2, f32));
  hv.w = f2bf((xv[3] - mean) * inv * rdf(gw, eoff + i0 + 3, f32) + rdf(bw, eoff + i0 + 3, f32));
  *(ushort4*)(h + (size_t)row * DIM + i0) = hv;
}

// ---------------- GEMM: C[M,N] = A[M,K] * Bt[N,K]^T ----------------
// MODE 0: bf16 = acc; 1: bf16 = relu(acc+bias); 2: fp32 = resid+acc+bias; 3: d_out per flag
template <int MODE>
__global__ __launch_bounds__(256) void gemm_bt(const bfu* __restrict__ A,
                                               const bfu* __restrict__ Bt,
                                               const void* __restrict__ bias, size_t beoff,
                                               const float* resid,
                                               void* outp,
                                               int M, int N, int K,
                                               const int* __restrict__ flag) {
  __shared__ __align__(16) bfu As[128 * 32];
  __shared__ __align__(16) bfu Bs[128 * 32];
  const bool f32 = *flag != 0;
  const int tid = threadIdx.x;
  const int lane = tid & 63, wave = tid >> 6;
  const int c = lane & 15, g = lane >> 4;
  const int m0 = blockIdx.y * 128, n0 = blockIdx.x * 128;
  const int wm = (wave & 1) * 64, wn = (wave >> 1) * 64;
  f32x4 acc[4][4] = {};
  const char* Ac = (const char*)A;
  const char* Bc = (const char*)Bt;
  const size_t stride = (size_t)K * 2;

  for (int kt = 0; kt < K; kt += 32) {
    __syncthreads();
#pragma unroll
    for (int i = 0; i < 2; ++i) {
      int fb = wave * 1024 + i * 4096;      // wave-uniform LDS base (bytes)
      int flat = fb + lane * 16;            // this lane's 16B
      int row = flat >> 6, colb = flat & 63;
      gload16(Ac + (size_t)(m0 + row) * stride + (size_t)kt * 2 + colb, (char*)As + fb);
      gload16(Bc + (size_t)(n0 + row) * stride + (size_t)kt * 2 + colb, (char*)Bs + fb);
    }
    asm volatile("s_waitcnt vmcnt(0)" ::: "memory");
    __syncthreads();
    s16x8 af[4], bfr[4];
#pragma unroll
    for (int mi = 0; mi < 4; ++mi)
      af[mi] = *(const s16x8*)&As[(wm + mi * 16 + c) * 32 + g * 8];
#pragma unroll
    for (int ni = 0; ni < 4; ++ni)
      bfr[ni] = *(const s16x8*)&Bs[(wn + ni * 16 + c) * 32 + g * 8];
#pragma unroll
    for (int mi = 0; mi < 4; ++mi)
#pragma unroll
      for (int ni = 0; ni < 4; ++ni)
        acc[mi][ni] = mfma32(af[mi], bfr[ni], acc[mi][ni]);
  }

#pragma unroll
  for (int mi = 0; mi < 4; ++mi) {
#pragma unroll
    for (int ni = 0; ni < 4; ++ni) {
      int col = n0 + wn + ni * 16 + c;
      float bv = bias ? rdf(bias, beoff + col, f32) : 0.0f;
#pragma unroll
      for (int jj = 0; jj < 4; ++jj) {
        int row = m0 + wm + mi * 16 + g * 4 + jj;
        float val = acc[mi][ni][jj] + bv;
        size_t oi = (size_t)row * N + col;
        if (MODE == 1) val = fmaxf(val, 0.0f);
        if (MODE == 2)      ((float*)outp)[oi] = resid[oi] + val;
        else if (MODE == 3) { if (f32) ((float*)outp)[oi] = val; else ((bfu*)outp)[oi] = f2bf(val); }
        else                ((bfu*)outp)[oi] = f2bf(val);
      }
    }
  }
}

// ---------------- flash attention ----------------
__global__ __launch_bounds__(64) void attn_kernel(const bfu* __restrict__ q,
                                                  const bfu* __restrict__ k,
                                                  const bfu* __restrict__ v,
                                                  bfu* __restrict__ o) {
  __shared__ __align__(16) bfu Plds[16 * 32];
  const int lane = threadIdx.x;
  const int c = lane & 15, g = lane >> 4;
  const int qt = blockIdx.x, hh = blockIdx.y, b = blockIdx.z;
  const int q0 = qt * 16;
  const float SENT = -1e30f;

  const size_t qbase = (size_t)(b * SEQ + q0 + c) * DIM + hh * HEADD + g * 8;
  s16x8 qf0 = *(const s16x8*)&q[qbase];
  s16x8 qf1 = *(const s16x8*)&q[qbase + 32];

  f32x4 oacc[4] = {};                // row q = q0+g*4+jj, col d = dg*16+c
  float mrun = SENT, lrun = 0.0f;    // stats for row q0+c (per lane)

  const int nkt = (q0 >> 5) + 1;
  for (int kt = 0; kt < nkt; ++kt) {
    const int k0 = kt * 32;
    const size_t kb0 = (size_t)(b * SEQ + k0 + c) * DIM + hh * HEADD + g * 8;
    const size_t kb1 = kb0 + (size_t)16 * DIM;
    s16x8 kf00 = *(const s16x8*)&k[kb0];
    s16x8 kf01 = *(const s16x8*)&k[kb0 + 32];
    s16x8 kf10 = *(const s16x8*)&k[kb1];
    s16x8 kf11 = *(const s16x8*)&k[kb1 + 32];
    f32x4 s0 = {}, s1 = {};
    s0 = mfma32(kf00, qf0, s0); s0 = mfma32(kf01, qf1, s0);  // S[q0+c][k0+g*4+jj]
    s1 = mfma32(kf10, qf0, s1); s1 = mfma32(kf11, qf1, s1);  // S[q0+c][k0+16+g*4+jj]

    float sv[8];
#pragma unroll
    for (int jj = 0; jj < 4; ++jj) {
      int ka = k0 + g * 4 + jj, kb = ka + 16;
      sv[jj]     = (ka <= q0 + c) ? s0[jj] * 0.125f : SENT;
      sv[4 + jj] = (kb <= q0 + c) ? s1[jj] * 0.125f : SENT;
    }
    float tmax = sv[0];
#pragma unroll
    for (int i = 1; i < 8; ++i) tmax = fmaxf(tmax, sv[i]);
    tmax = fmaxf(tmax, __shfl_xor(tmax, 16));
    tmax = fmaxf(tmax, __shfl_xor(tmax, 32));
    float mnew = fmaxf(mrun, tmax);
    float alpha = __expf(mrun - mnew);
    float p[8], psum = 0.0f;
#pragma unroll
    for (int i = 0; i < 8; ++i) { p[i] = __expf(sv[i] - mnew); psum += p[i]; }
    psum += __shfl_xor(psum, 16);
    psum += __shfl_xor(psum, 32);
    lrun = lrun * alpha + psum;
    mrun = mnew;

    // P -> LDS, same-typed accesses + barriers (TBAA-safe, ordering-safe)
    ushort4 w0; w0.x = f2bf(p[0]); w0.y = f2bf(p[1]); w0.z = f2bf(p[2]); w0.w = f2bf(p[3]);
    ushort4 w1; w1.x = f2bf(p[4]); w1.y = f2bf(p[5]); w1.z = f2bf(p[6]); w1.w = f2bf(p[7]);
    *(ushort4*)&Plds[c * 32 + g * 4] = w0;
    *(ushort4*)&Plds[c * 32 + 16 + g * 4] = w1;
    __syncthreads();

    float aq[4];
#pragma unroll
    for (int jj = 0; jj < 4; ++jj) aq[jj] = __shfl(alpha, g * 4 + jj);

    ushort4 ra = *(const ushort4*)&Plds[c * 32 + g * 8];
    ushort4 rb = *(const ushort4*)&Plds[c * 32 + g * 8 + 4];
    s16x8 pa = {(short)ra.x, (short)ra.y, (short)ra.z, (short)ra.w,
                (short)rb.x, (short)rb.y, (short)rb.z, (short)rb.w};
    __syncthreads();

#pragma unroll
    for (int dg = 0; dg < 4; ++dg) {
      s16x8 vf;
#pragma unroll
      for (int j = 0; j < 8; ++j)
        vf[j] = (short)v[(size_t)(b * SEQ + k0 + g * 8 + j) * DIM + hh * HEADD + dg * 16 + c];
#pragma unroll
      for (int jj = 0; jj < 4; ++jj) oacc[dg][jj] *= aq[jj];
      oacc[dg] = mfma32(pa, vf, oacc[dg]);
    }
  }

  float lq[4];
#pragma unroll
  for (int jj = 0; jj < 4; ++jj) lq[jj] = __shfl(lrun, g * 4 + jj);
#pragma unroll
  for (int dg = 0; dg < 4; ++dg)
#pragma unroll
    for (int jj = 0; jj < 4; ++jj) {
      size_t oi = (size_t)(b * SEQ + q0 + g * 4 + jj) * DIM + hh * HEADD + dg * 16 + c;
      o[oi] = f2bf(oacc[dg][jj] / lq[jj]);
    }
}

// ---------------- per-row NLL ----------------
__global__ __launch_bounds__(256) void nll_kernel(const void* __restrict__ logits,
                                                  const int* __restrict__ tgt,
                                                  const int* __restrict__ flag,
                                                  float* __restrict__ nll) {
  const bool f32 = *flag != 0;
  int row = blockIdx.x;
  float m = -3.0e38f, s = 0.0f;
  for (int i = threadIdx.x * 4; i < VOCAB; i += 1024) {
    float x[4];
    if (f32) {
      float4 u = *(const float4*)((const float*)logits + (size_t)row * VOCAB + i);
      x[0] = u.x; x[1] = u.y; x[2] = u.z; x[3] = u.w;
    } else {
      ushort4 u = *(const ushort4*)((const bfu*)logits + (size_t)row * VOCAB + i);
      x[0] = bf2f(u.x); x[1] = bf2f(u.y); x[2] = bf2f(u.z); x[3] = bf2f(u.w);
    }
#pragma unroll
    for (int j = 0; j < 4; ++j) {
      float nm = fmaxf(m, x[j]);
      s = s * __expf(m - nm) + __expf(x[j] - nm);
      m = nm;
    }
  }
  for (int off = 32; off; off >>= 1) {
    float om = __shfl_xor(m, off), os = __shfl_xor(s, off);
    float nm = fmaxf(m, om);
    s = s * __expf(m - nm) + os * __expf(om - nm);
    m = nm;
  }
  __shared__ float rm[4], rsh[4];
  int wave = threadIdx.x >> 6;
  if ((threadIdx.x & 63) == 0) { rm[wave] = m; rsh[wave] = s; }
  __syncthreads();
  if (threadIdx.x == 0) {
    float M = rm[0], S = rsh[0];
    for (int w = 1; w < 4; ++w) {
      float nm = fmaxf(M, rm[w]);
      S = S * __expf(M - nm) + rsh[w] * __expf(rm[w] - nm);
      M = nm;
    }
    nll[row] = (M + __logf(S)) - rdf(logits, (size_t)row * VOCAB + tgt[row], f32);
  }
}

__global__ __launch_bounds__(256) void loss_kernel(const float* __restrict__ nll,
                                                   void* __restrict__ out,
                                                   const int* __restrict__ flag) {
  float s = 0.0f;
  for (int i = threadIdx.x; i < NROW; i += 256) s += nll[i];
  for (int off = 32; off; off >>= 1) s += __shfl_xor(s, off);
  __shared__ float r[4];
  int wave = threadIdx.x >> 6;
  if ((threadIdx.x & 63) == 0) r[wave] = s;
  __syncthreads();
  if (threadIdx.x == 0) {
    float v = (r[0] + r[1] + r[2] + r[3]) * (1.0f / NROW);
    size_t i = (size_t)NROW * VOCAB;
    if (*flag) ((float*)out)[i] = v; else ((bfu*)out)[i] = f2bf(v);
  }
}

// ---------------- host ----------------
extern "C" void kernel_launch(void* const* d_in, const int* in_sizes, int n_in,
                              void* d_out, int out_size, void* d_ws, size_t ws_size,
                              hipStream_t stream) {
  (void)in_sizes; (void)n_in; (void)out_size;
  const int* idx      = (const int*)d_in[0];
  const int* targets  = (const int*)d_in[1];
  const void* tok_emb = d_in[2];
  const void* pos_emb = d_in[3];
  const void* wq      = d_in[4];
  const void* wk      = d_in[5];
  const void* wv      = d_in[6];
  const void* w_proj  = d_in[7];
  const void* b_proj  = d_in[8];
  const void* w_fc1   = d_in[9];
  const void* b_fc1   = d_in[10];
  const void* w_fc2   = d_in[11];
  const void* b_fc2   = d_in[12];
  const void* ln1_g   = d_in[13];
  const void* ln1_b   = d_in[14];
  const void* ln2_g   = d_in[15];
  const void* ln2_b   = d_in[16];
  const void* lnf_g   = d_in[17];
  const void* lnf_b   = d_in[18];
  const void* w_head  = d_in[19];
  const void* b_head  = d_in[20];

  char* ws = (char*)d_ws;
  size_t off = 0;
  auto alloc = [&](size_t bytes) {
    char* p = ws + off;
    off += (bytes + 255) & ~(size_t)255;
    return p;
  };
  int* dflag = (int*)alloc(256);
  float* xf  = (float*)alloc((size_t)NROW * DIM * 4);
  bfu* hbuf  = (bfu*)alloc((size_t)NROW * DIM * 2);
  bfu* qb    = (bfu*)alloc((size_t)NROW * DIM * 2);
  bfu* kb    = (bfu*)alloc((size_t)NROW * DIM * 2);
  bfu* vbuf  = (bfu*)alloc((size_t)NROW * DIM * 2);
  bfu* ob    = (bfu*)alloc((size_t)NROW * DIM * 2);
  bfu* ub    = (bfu*)alloc((size_t)NROW * FF * 2);
  bfu* wqT   = (bfu*)alloc((size_t)DIM * DIM * 2);
  bfu* wkT   = (bfu*)alloc((size_t)DIM * DIM * 2);
  bfu* wvT   = (bfu*)alloc((size_t)DIM * DIM * 2);
  bfu* wpT   = (bfu*)alloc((size_t)DIM * DIM * 2);
  bfu* f1T   = (bfu*)alloc((size_t)DIM * FF * 2);
  bfu* f2T   = (bfu*)alloc((size_t)DIM * FF * 2);
  bfu* hT    = (bfu*)alloc((size_t)DIM * VOCAB * 2);
  float* nll = (float*)alloc((size_t)NROW * 4);
  if (off > ws_size) return;

  detect_kernel<<<1, 256, 0, stream>>>((const unsigned*)tok_emb, dflag);

  dim3 tb(32, 8);
  tkernel<<<dim3(VOCAB / 32, DIM / 32), tb, 0, stream>>>(w_head, 0, hT, DIM, VOCAB, dflag);
  embed_kernel<<<NROW, 256, 0, stream>>>(idx, tok_emb, pos_emb, dflag, xf);

  for (int l = 0; l < LAYERS; ++l) {
    const size_t wo = (size_t)l * DIM * DIM, fo = (size_t)l * DIM * FF;
    const size_t dof = (size_t)l * DIM, ffo = (size_t)l * FF;
    tkernel<<<dim3(DIM / 32, DIM / 32), tb, 0, stream>>>(wq, wo, wqT, DIM, DIM, dflag);
    tkernel<<<dim3(DIM / 32, DIM / 32), tb, 0, stream>>>(wk, wo, wkT, DIM, DIM, dflag);
    tkernel<<<dim3(DIM / 32, DIM / 32), tb, 0, stream>>>(wv, wo, wvT, DIM, DIM, dflag);
    tkernel<<<dim3(DIM / 32, DIM / 32), tb, 0, stream>>>(w_proj, wo, wpT, DIM, DIM, dflag);
    tkernel<<<dim3(FF / 32, DIM / 32), tb, 0, stream>>>(w_fc1, fo, f1T, DIM, FF, dflag);
    tkernel<<<dim3(DIM / 32, FF / 32), tb, 0, stream>>>(w_fc2, fo, f2T, FF, DIM, dflag);

    ln_kernel<<<NROW, 256, 0, stream>>>(xf, ln1_g, ln1_b, dof, dflag, hbuf);
    gemm_bt<0><<<dim3(DIM / 128, NROW / 128), 256, 0, stream>>>(
        hbuf, wqT, nullptr, 0, nullptr, qb, NROW, DIM, DIM, dflag);
    gemm_bt<0><<<dim3(DIM / 128, NROW / 128), 256, 0, stream>>>(
        hbuf, wkT, nullptr, 0, nullptr, kb, NROW, DIM, DIM, dflag);
    gemm_bt<0><<<dim3(DIM / 128, NROW / 128), 256, 0, stream>>>(
        hbuf, wvT, nullptr, 0, nullptr, vbuf, NROW, DIM, DIM, dflag);
    attn_kernel<<<dim3(SEQ / 16, NH, NBATCH), 64, 0, stream>>>(qb, kb, vbuf, ob);
    gemm_bt<2><<<dim3(DIM / 128, NROW / 128), 256, 0, stream>>>(
        ob, wpT, b_proj, dof, xf, xf, NROW, DIM, DIM, dflag);
    ln_kernel<<<NROW, 256, 0, stream>>>(xf, ln2_g, ln2_b, dof, dflag, hbuf);
    gemm_bt<1><<<dim3(FF / 128, NROW / 128), 256, 0, stream>>>(
        hbuf, f1T, b_fc1, ffo, nullptr, ub, NROW, FF, DIM, dflag);
    gemm_bt<2><<<dim3(DIM / 128, NROW / 128), 256, 0, stream>>>(
        ub, f2T, b_fc2, dof, xf, xf, NROW, DIM, FF, dflag);
  }

  ln_kernel<<<NROW, 256, 0, stream>>>(xf, lnf_g, lnf_b, 0, dflag, hbuf);
  gemm_bt<3><<<dim3(VOCAB / 128, NROW / 128), 256, 0, stream>>>(
      hbuf, hT, b_head, 0, nullptr, d_out, NROW, VOCAB, DIM, dflag);
  nll_kernel<<<NROW, 256, 0, stream>>>(d_out, targets, dflag, nll);
  loss_kernel<<<1, 256, 0, stream>>>(nll, d_out, dflag);
}

// Round 4
// 3114.426 us; speedup vs baseline: 1.2073x; 1.2073x over previous
//
#include <hip/hip_runtime.h>

#define LAYERS 6
#define NH 16
#define DIM 1024
#define VOCAB 32000
#define SEQ 2048
#define NBATCH 2
#define HEADD 64
#define NROW (NBATCH*SEQ)   // 4096
#define FF 4096
#define QKVS 3072
#define LN_EPS 1e-5f

typedef unsigned short bfu;  // bf16 bits
typedef __attribute__((ext_vector_type(8))) short s16x8;
typedef __attribute__((ext_vector_type(4))) float f32x4;

__device__ __forceinline__ float bf2f(bfu u) { return __uint_as_float(((unsigned)u) << 16); }
__device__ __forceinline__ bfu f2bf(float x) {
  unsigned u = __float_as_uint(x);
  return (bfu)((u + 0x7fffu + ((u >> 16) & 1u)) >> 16);  // RNE
}

__device__ __forceinline__ void gload16(const void* g, void* l) {
  __builtin_amdgcn_global_load_lds((const __attribute__((address_space(1))) void*)g,
                                   (__attribute__((address_space(3))) void*)l, 16, 0, 0);
}

__device__ __forceinline__ f32x4 mfma32(s16x8 a, s16x8 b, f32x4 c) {
  return __builtin_amdgcn_mfma_f32_16x16x32_bf16(a, b, c, 0, 0, 0);
}

// ---------------- transpose+convert: out[C][R] (bf16) = in[R][C]^T (fp32) ----------------
__global__ __launch_bounds__(256) void tkernel(const float* __restrict__ in,
                                               bfu* __restrict__ out, int R, int C) {
  __shared__ bfu tile[32][33];
  int tx = threadIdx.x, ty = threadIdx.y;
  int bx = blockIdx.x * 32, by = blockIdx.y * 32;
#pragma unroll
  for (int i = 0; i < 4; ++i)
    tile[ty + i * 8][tx] = f2bf(in[(size_t)(by + ty + i * 8) * C + bx + tx]);
  __syncthreads();
#pragma unroll
  for (int i = 0; i < 4; ++i)
    out[(size_t)(bx + ty + i * 8) * R + by + tx] = tile[tx][ty + i * 8];
}

// batched q/k/v transpose into concatenated qkvT[3072][1024] (z selects source)
__global__ __launch_bounds__(256) void tkernel_qkv(const float* __restrict__ wq,
                                                   const float* __restrict__ wk,
                                                   const float* __restrict__ wv,
                                                   bfu* __restrict__ out) {
  __shared__ bfu tile[32][33];
  const float* in = blockIdx.z == 0 ? wq : blockIdx.z == 1 ? wk : wv;
  bfu* op = out + (size_t)blockIdx.z * DIM * DIM;
  int tx = threadIdx.x, ty = threadIdx.y;
  int bx = blockIdx.x * 32, by = blockIdx.y * 32;
#pragma unroll
  for (int i = 0; i < 4; ++i)
    tile[ty + i * 8][tx] = f2bf(in[(size_t)(by + ty + i * 8) * DIM + bx + tx]);
  __syncthreads();
#pragma unroll
  for (int i = 0; i < 4; ++i)
    op[(size_t)(bx + ty + i * 8) * DIM + by + tx] = tile[tx][ty + i * 8];
}

// ---------------- embedding: xf[row,d] = tok[idx[row],d] + pos[row%SEQ,d] (fp32) ----------------
__global__ __launch_bounds__(256) void embed_kernel(const int* __restrict__ idx,
                                                    const float* __restrict__ tok,
                                                    const float* __restrict__ pos,
                                                    float* __restrict__ xf) {
  int row = blockIdx.x;
  int t = row % SEQ;
  int tokid = idx[row];
  int d0 = threadIdx.x * 4;
  float4 tv = *(const float4*)&tok[(size_t)tokid * DIM + d0];
  float4 pv = *(const float4*)&pos[(size_t)t * DIM + d0];
  float4 r;
  r.x = tv.x + pv.x; r.y = tv.y + pv.y; r.z = tv.z + pv.z; r.w = tv.w + pv.w;
  *(float4*)&xf[(size_t)row * DIM + d0] = r;
}

// ---------------- LayerNorm: x fp32 -> h bf16 ----------------
__global__ __launch_bounds__(256) void ln_kernel(const float* __restrict__ xf,
                                                 const float* __restrict__ gw,
                                                 const float* __restrict__ bw,
                                                 bfu* __restrict__ h) {
  int row = blockIdx.x, tid = threadIdx.x;
  const float* xr = xf + (size_t)row * DIM;
  float4 xv4 = ((const float4*)xr)[tid];
  float xv[4] = {xv4.x, xv4.y, xv4.z, xv4.w};
  float s = xv[0] + xv[1] + xv[2] + xv[3];
  float ss = xv[0]*xv[0] + xv[1]*xv[1] + xv[2]*xv[2] + xv[3]*xv[3];
  for (int o = 32; o; o >>= 1) { s += __shfl_xor(s, o); ss += __shfl_xor(ss, o); }
  __shared__ float red[8];
  int wave = tid >> 6;
  if ((tid & 63) == 0) { red[wave * 2] = s; red[wave * 2 + 1] = ss; }
  __syncthreads();
  s  = red[0] + red[2] + red[4] + red[6];
  ss = red[1] + red[3] + red[5] + red[7];
  float mean = s * (1.0f / DIM);
  float var = ss * (1.0f / DIM) - mean * mean;
  float inv = rsqrtf(var + LN_EPS);
  int i0 = tid * 4;
  float4 gv = ((const float4*)gw)[tid];
  float4 bv = ((const float4*)bw)[tid];
  ushort4 hv;
  hv.x = f2bf((xv[0] - mean) * inv * gv.x + bv.x);
  hv.y = f2bf((xv[1] - mean) * inv * gv.y + bv.y);
  hv.z = f2bf((xv[2] - mean) * inv * gv.z + bv.z);
  hv.w = f2bf((xv[3] - mean) * inv * gv.w + bv.w);
  *(ushort4*)(h + (size_t)row * DIM + i0) = hv;
}

// ---------------- GEMM: C[M,N] = A[M,K] * Bt[N,K]^T ; 128x128xBK32 + XCD swizzle ----------------
// MODE 0: bf16 = acc(+bias); 1: bf16 = relu(acc+bias); 2: fp32 = resid+acc+bias; 3: fp32 = acc+bias
template <int MODE>
__global__ __launch_bounds__(256) void gemm_bt(const bfu* __restrict__ A,
                                               const bfu* __restrict__ Bt,
                                               const float* __restrict__ bias,
                                               const float* resid,
                                               void* outp,
                                               int M, int N, int K,
                                               int colchunk) {
  __shared__ __align__(16) bfu As[128 * 32];
  __shared__ __align__(16) bfu Bs[128 * 32];
  const int tid = threadIdx.x;
  const int lane = tid & 63, wave = tid >> 6;
  const int c = lane & 15, g = lane >> 4;

  // XCD-aware bijective swizzle (requires gridDim.x*gridDim.y % 8 == 0).
  // colchunk=1: linearize column-major -> each XCD gets a contiguous span of N-tiles
  //             (use when B is the big operand, e.g. the head GEMM).
  // colchunk=0: row-major -> each XCD gets a contiguous span of M-tiles (A big).
  const int gx = gridDim.x, gy = gridDim.y;
  const int nwg = gx * gy;
  int bid = colchunk ? (blockIdx.x * gy + blockIdx.y) : (blockIdx.y * gx + blockIdx.x);
  const int cpx = nwg >> 3;
  int swz = (bid & 7) * cpx + (bid >> 3);
  int bx, by;
  if (colchunk) { bx = swz / gy; by = swz - bx * gy; }
  else          { by = swz / gx; bx = swz - by * gx; }

  const int m0 = by * 128, n0 = bx * 128;
  const int wm = (wave & 1) * 64, wn = (wave >> 1) * 64;
  f32x4 acc[4][4] = {};
  const char* Ac = (const char*)A;
  const char* Bc = (const char*)Bt;
  const size_t stride = (size_t)K * 2;

  for (int kt = 0; kt < K; kt += 32) {
    __syncthreads();
#pragma unroll
    for (int i = 0; i < 2; ++i) {
      int fb = wave * 1024 + i * 4096;      // wave-uniform LDS base (bytes)
      int flat = fb + lane * 16;            // this lane's 16B
      int row = flat >> 6, colb = flat & 63;
      gload16(Ac + (size_t)(m0 + row) * stride + (size_t)kt * 2 + colb, (char*)As + fb);
      gload16(Bc + (size_t)(n0 + row) * stride + (size_t)kt * 2 + colb, (char*)Bs + fb);
    }
    asm volatile("s_waitcnt vmcnt(0)" ::: "memory");
    __syncthreads();
    s16x8 af[4], bfr[4];
#pragma unroll
    for (int mi = 0; mi < 4; ++mi)
      af[mi] = *(const s16x8*)&As[(wm + mi * 16 + c) * 32 + g * 8];
#pragma unroll
    for (int ni = 0; ni < 4; ++ni)
      bfr[ni] = *(const s16x8*)&Bs[(wn + ni * 16 + c) * 32 + g * 8];
#pragma unroll
    for (int mi = 0; mi < 4; ++mi)
#pragma unroll
      for (int ni = 0; ni < 4; ++ni)
        acc[mi][ni] = mfma32(af[mi], bfr[ni], acc[mi][ni]);
  }

#pragma unroll
  for (int mi = 0; mi < 4; ++mi) {
#pragma unroll
    for (int ni = 0; ni < 4; ++ni) {
      int col = n0 + wn + ni * 16 + c;
      float bv = bias ? bias[col] : 0.0f;
#pragma unroll
      for (int jj = 0; jj < 4; ++jj) {
        int row = m0 + wm + mi * 16 + g * 4 + jj;
        float val = acc[mi][ni][jj] + bv;
        size_t oi = (size_t)row * N + col;
        if (MODE == 1) val = fmaxf(val, 0.0f);
        if (MODE == 2)      ((float*)outp)[oi] = resid[oi] + val;
        else if (MODE == 3) ((float*)outp)[oi] = val;
        else                ((bfu*)outp)[oi] = f2bf(val);
      }
    }
  }
}

// ---------------- flash attention: 1 wave per (16-row q-tile, head, batch); 32-key tiles ----------
// q/k/v live in fused qkv buffer [NROW][3072] (q|k|v). V staged via global_load_lds.
__global__ __launch_bounds__(64) void attn_kernel(const bfu* __restrict__ qkv,
                                                  bfu* __restrict__ o) {
  __shared__ __align__(16) bfu Plds[16 * 32];
  __shared__ __align__(16) bfu Vs[32 * 64];
  const int lane = threadIdx.x;
  const int c = lane & 15, g = lane >> 4;
  const int qt = blockIdx.x, hh = blockIdx.y, b = blockIdx.z;
  const int q0 = qt * 16;
  const float SENT = -1e30f;

  const size_t rowb = (size_t)b * SEQ;
  const size_t qbase = (rowb + q0 + c) * QKVS + hh * HEADD + g * 8;
  s16x8 qf0 = *(const s16x8*)&qkv[qbase];
  s16x8 qf1 = *(const s16x8*)&qkv[qbase + 32];
  const char* vch = (const char*)(qkv + 2048 + rowb * QKVS + hh * HEADD);

  f32x4 oacc[4] = {};                // row q = q0+g*4+jj, col d = dg*16+c
  float mrun = SENT, lrun = 0.0f;    // stats for row q0+c (per lane)

  const int nkt = (q0 >> 5) + 1;
  for (int kt = 0; kt < nkt; ++kt) {
    const int k0 = kt * 32;
    // stage V[k0..k0+31][64] (bf16, 4KB) into LDS via coalesced global_load_lds
#pragma unroll
    for (int i = 0; i < 4; ++i) {
      int flat = i * 1024 + lane * 16;
      int r = flat >> 7, cb = flat & 127;
      gload16(vch + (size_t)(k0 + r) * (QKVS * 2) + cb, (char*)Vs + i * 1024);
    }
    const size_t kb0 = (rowb + k0 + c) * QKVS + 1024 + hh * HEADD + g * 8;
    const size_t kb1 = kb0 + (size_t)16 * QKVS;
    s16x8 kf00 = *(const s16x8*)&qkv[kb0];
    s16x8 kf01 = *(const s16x8*)&qkv[kb0 + 32];
    s16x8 kf10 = *(const s16x8*)&qkv[kb1];
    s16x8 kf11 = *(const s16x8*)&qkv[kb1 + 32];
    f32x4 s0 = {}, s1 = {};
    s0 = mfma32(kf00, qf0, s0); s0 = mfma32(kf01, qf1, s0);  // S[q0+c][k0+g*4+jj]
    s1 = mfma32(kf10, qf0, s1); s1 = mfma32(kf11, qf1, s1);  // S[q0+c][k0+16+g*4+jj]

    float sv[8];
#pragma unroll
    for (int jj = 0; jj < 4; ++jj) {
      int ka = k0 + g * 4 + jj, kb = ka + 16;
      sv[jj]     = (ka <= q0 + c) ? s0[jj] * 0.125f : SENT;
      sv[4 + jj] = (kb <= q0 + c) ? s1[jj] * 0.125f : SENT;
    }
    float tmax = sv[0];
#pragma unroll
    for (int i = 1; i < 8; ++i) tmax = fmaxf(tmax, sv[i]);
    tmax = fmaxf(tmax, __shfl_xor(tmax, 16));
    tmax = fmaxf(tmax, __shfl_xor(tmax, 32));
    float mnew = fmaxf(mrun, tmax);
    float alpha = __expf(mrun - mnew);
    float p[8], psum = 0.0f;
#pragma unroll
    for (int i = 0; i < 8; ++i) { p[i] = __expf(sv[i] - mnew); psum += p[i]; }
    psum += __shfl_xor(psum, 16);
    psum += __shfl_xor(psum, 32);
    lrun = lrun * alpha + psum;
    mrun = mnew;

    // P -> LDS roundtrip into x32 A-fragment layout (TBAA-safe same-typed accesses)
    ushort4 w0; w0.x = f2bf(p[0]); w0.y = f2bf(p[1]); w0.z = f2bf(p[2]); w0.w = f2bf(p[3]);
    ushort4 w1; w1.x = f2bf(p[4]); w1.y = f2bf(p[5]); w1.z = f2bf(p[6]); w1.w = f2bf(p[7]);
    *(ushort4*)&Plds[c * 32 + g * 4] = w0;
    *(ushort4*)&Plds[c * 32 + 16 + g * 4] = w1;
    __syncthreads();

    float aq[4];
#pragma unroll
    for (int jj = 0; jj < 4; ++jj) aq[jj] = __shfl(alpha, g * 4 + jj);

    ushort4 ra = *(const ushort4*)&Plds[c * 32 + g * 8];
    ushort4 rb = *(const ushort4*)&Plds[c * 32 + g * 8 + 4];
    s16x8 pa = {(short)ra.x, (short)ra.y, (short)ra.z, (short)ra.w,
                (short)rb.x, (short)rb.y, (short)rb.z, (short)rb.w};
    __syncthreads();

    asm volatile("s_waitcnt vmcnt(0)" ::: "memory");  // V tile resident in LDS
#pragma unroll
    for (int dg = 0; dg < 4; ++dg) {
      s16x8 vf;
#pragma unroll
      for (int j = 0; j < 8; ++j)
        vf[j] = (short)Vs[(g * 8 + j) * 64 + dg * 16 + c];
#pragma unroll
      for (int jj = 0; jj < 4; ++jj) oacc[dg][jj] *= aq[jj];
      oacc[dg] = mfma32(pa, vf, oacc[dg]);
    }
  }

  float lq[4];
#pragma unroll
  for (int jj = 0; jj < 4; ++jj) lq[jj] = __shfl(lrun, g * 4 + jj);
#pragma unroll
  for (int dg = 0; dg < 4; ++dg)
#pragma unroll
    for (int jj = 0; jj < 4; ++jj) {
      size_t oi = (size_t)(rowb + q0 + g * 4 + jj) * DIM + hh * HEADD + dg * 16 + c;
      o[oi] = f2bf(oacc[dg][jj] / lq[jj]);
    }
}

// ---------------- per-row NLL (fp32 logits) ----------------
__global__ __launch_bounds__(256) void nll_kernel(const float* __restrict__ logits,
                                                  const int* __restrict__ tgt,
                                                  float* __restrict__ nll) {
  int row = blockIdx.x;
  const float* lp = logits + (size_t)row * VOCAB;
  float m = -3.0e38f, s = 0.0f;
  for (int i = threadIdx.x * 4; i < VOCAB; i += 1024) {
    float4 u = *(const float4*)(lp + i);
    float x[4] = {u.x, u.y, u.z, u.w};
#pragma unroll
    for (int j = 0; j < 4; ++j) {
      float nm = fmaxf(m, x[j]);
      s = s * __expf(m - nm) + __expf(x[j] - nm);
      m = nm;
    }
  }
  for (int off = 32; off; off >>= 1) {
    float om = __shfl_xor(m, off), os = __shfl_xor(s, off);
    float nm = fmaxf(m, om);
    s = s * __expf(m - nm) + os * __expf(om - nm);
    m = nm;
  }
  __shared__ float rm[4], rsh[4];
  int wave = threadIdx.x >> 6;
  if ((threadIdx.x & 63) == 0) { rm[wave] = m; rsh[wave] = s; }
  __syncthreads();
  if (threadIdx.x == 0) {
    float M = rm[0], S = rsh[0];
    for (int w = 1; w < 4; ++w) {
      float nm = fmaxf(M, rm[w]);
      S = S * __expf(M - nm) + rsh[w] * __expf(rm[w] - nm);
      M = nm;
    }
    nll[row] = (M + __logf(S)) - lp[tgt[row]];
  }
}

__global__ __launch_bounds__(256) void loss_kernel(const float* __restrict__ nll,
                                                   float* __restrict__ out) {
  float s = 0.0f;
  for (int i = threadIdx.x; i < NROW; i += 256) s += nll[i];
  for (int off = 32; off; off >>= 1) s += __shfl_xor(s, off);
  __shared__ float r[4];
  int wave = threadIdx.x >> 6;
  if ((threadIdx.x & 63) == 0) r[wave] = s;
  __syncthreads();
  if (threadIdx.x == 0) out[(size_t)NROW * VOCAB] = (r[0] + r[1] + r[2] + r[3]) * (1.0f / NROW);
}

// ---------------- host ----------------
extern "C" void kernel_launch(void* const* d_in, const int* in_sizes, int n_in,
                              void* d_out, int out_size, void* d_ws, size_t ws_size,
                              hipStream_t stream) {
  (void)in_sizes; (void)n_in; (void)out_size;
  const int* idx       = (const int*)d_in[0];
  const int* targets   = (const int*)d_in[1];
  const float* tok_emb = (const float*)d_in[2];
  const float* pos_emb = (const float*)d_in[3];
  const float* wq      = (const float*)d_in[4];
  const float* wk      = (const float*)d_in[5];
  const float* wv      = (const float*)d_in[6];
  const float* w_proj  = (const float*)d_in[7];
  const float* b_proj  = (const float*)d_in[8];
  const float* w_fc1   = (const float*)d_in[9];
  const float* b_fc1   = (const float*)d_in[10];
  const float* w_fc2   = (const float*)d_in[11];
  const float* b_fc2   = (const float*)d_in[12];
  const float* ln1_g   = (const float*)d_in[13];
  const float* ln1_b   = (const float*)d_in[14];
  const float* ln2_g   = (const float*)d_in[15];
  const float* ln2_b   = (const float*)d_in[16];
  const float* lnf_g   = (const float*)d_in[17];
  const float* lnf_b   = (const float*)d_in[18];
  const float* w_head  = (const float*)d_in[19];
  const float* b_head  = (const float*)d_in[20];

  char* ws = (char*)d_ws;
  size_t off = 0;
  auto alloc = [&](size_t bytes) {
    char* p = ws + off;
    off += (bytes + 255) & ~(size_t)255;
    return p;
  };
  float* xf  = (float*)alloc((size_t)NROW * DIM * 4);
  bfu* hbuf  = (bfu*)alloc((size_t)NROW * DIM * 2);
  bfu* qkvb  = (bfu*)alloc((size_t)NROW * QKVS * 2);
  bfu* ob    = (bfu*)alloc((size_t)NROW * DIM * 2);
  bfu* ub    = (bfu*)alloc((size_t)NROW * FF * 2);
  bfu* qkvT  = (bfu*)alloc((size_t)QKVS * DIM * 2);  // wq^T|wk^T|wv^T
  bfu* wpT   = (bfu*)alloc((size_t)DIM * DIM * 2);
  bfu* f1T   = (bfu*)alloc((size_t)DIM * FF * 2);
  bfu* f2T   = (bfu*)alloc((size_t)DIM * FF * 2);
  bfu* hT    = (bfu*)alloc((size_t)DIM * VOCAB * 2);
  float* nll = (float*)alloc((size_t)NROW * 4);
  if (off > ws_size) return;

  dim3 tb(32, 8);
  tkernel<<<dim3(VOCAB / 32, DIM / 32), tb, 0, stream>>>(w_head, hT, DIM, VOCAB);
  embed_kernel<<<NROW, 256, 0, stream>>>(idx, tok_emb, pos_emb, xf);

  float* logits = (float*)d_out;
  for (int l = 0; l < LAYERS; ++l) {
    const size_t wo = (size_t)l * DIM * DIM, fo = (size_t)l * DIM * FF;
    tkernel_qkv<<<dim3(DIM / 32, DIM / 32, 3), tb, 0, stream>>>(wq + wo, wk + wo, wv + wo, qkvT);
    tkernel<<<dim3(DIM / 32, DIM / 32), tb, 0, stream>>>(w_proj + wo, wpT, DIM, DIM);
    tkernel<<<dim3(FF / 32, DIM / 32), tb, 0, stream>>>(w_fc1 + fo, f1T, DIM, FF);
    tkernel<<<dim3(DIM / 32, FF / 32), tb, 0, stream>>>(w_fc2 + fo, f2T, FF, DIM);

    ln_kernel<<<NROW, 256, 0, stream>>>(xf, ln1_g + l * DIM, ln1_b + l * DIM, hbuf);
    gemm_bt<0><<<dim3(QKVS / 128, NROW / 128), 256, 0, stream>>>(
        hbuf, qkvT, nullptr, nullptr, qkvb, NROW, QKVS, DIM, 0);
    attn_kernel<<<dim3(SEQ / 16, NH, NBATCH), 64, 0, stream>>>(qkvb, ob);
    gemm_bt<2><<<dim3(DIM / 128, NROW / 128), 256, 0, stream>>>(
        ob, wpT, b_proj + l * DIM, xf, xf, NROW, DIM, DIM, 0);
    ln_kernel<<<NROW, 256, 0, stream>>>(xf, ln2_g + l * DIM, ln2_b + l * DIM, hbuf);
    gemm_bt<1><<<dim3(FF / 128, NROW / 128), 256, 0, stream>>>(
        hbuf, f1T, b_fc1 + l * FF, nullptr, ub, NROW, FF, DIM, 0);
    gemm_bt<2><<<dim3(DIM / 128, NROW / 128), 256, 0, stream>>>(
        ub, f2T, b_fc2 + l * DIM, xf, xf, NROW, DIM, FF, 0);
  }

  ln_kernel<<<NROW, 256, 0, stream>>>(xf, lnf_g, lnf_b, hbuf);
  gemm_bt<3><<<dim3(VOCAB / 128, NROW / 128), 256, 0, stream>>>(
      hbuf, hT, b_head, nullptr, logits, NROW, VOCAB, DIM, 1);
  nll_kernel<<<NROW, 256, 0, stream>>>(logits, targets, nll);
  loss_kernel<<<1, 256, 0, stream>>>(nll, logits);
}